// Round 4
// baseline (233.846 us; speedup 1.0000x reference)
//
#include <hip/hip_runtime.h>

#define B_  16
#define N_  4096
#define M_  1024
#define C1_ 128
#define C2_ 256
#define K0_ 384   // C2 + C1
#define O1_ 256
#define O2_ 256

typedef _Float16 half4  __attribute__((ext_vector_type(4)));
typedef _Float16 half8  __attribute__((ext_vector_type(8)));
typedef float    f32x4  __attribute__((ext_vector_type(4)));

// ---------------------------------------------------------------------------
// three_nn v4: LDS xyz2 as {x,y,z,|p|^2}, 8 chunks x 128 pts, 8 threads/query.
// EXACT fp32 distances; sorted-insert via fmin + 2x med3 (values) and
// cmp/cndmask off OLD keys (indices). 3-step butterfly merge; surviving lane
// (c==0) always merges lower-index chunks first => top_k tie order preserved.
// ---------------------------------------------------------------------------
__global__ __launch_bounds__(256)
void three_nn_kernel(const float* __restrict__ xyz1, const float* __restrict__ xyz2,
                     int* __restrict__ idxb, float* __restrict__ wb) {
    __shared__ float pts[8 * 516];   // 8 chunks x 128 pts x 4 floats (+4 pad)
    int b = blockIdx.y;
    int t = threadIdx.x;
    {
        const float* src = xyz2 + (size_t)b * 3 * M_;
        int m0 = t * 4;
        f32x4 xv = *(const f32x4*)(src + m0);
        f32x4 yv = *(const f32x4*)(src + M_ + m0);
        f32x4 zv = *(const f32x4*)(src + 2 * M_ + m0);
        float* dst = pts + (m0 >> 7) * 516 + (m0 & 127) * 4;
#pragma unroll
        for (int jj = 0; jj < 4; ++jj) {
            f32x4 o = {xv[jj], yv[jj], zv[jj],
                       fmaf(xv[jj], xv[jj], fmaf(yv[jj], yv[jj], zv[jj] * zv[jj]))};
            *(f32x4*)(dst + jj * 4) = o;
        }
    }
    __syncthreads();
    int lane = t & 63;
    int c = lane & 7;                        // chunk 0..7
    int q = ((t >> 6) << 3) + (lane >> 3);   // query within block 0..31
    int n = blockIdx.x * 32 + q;
    const float* qp = xyz1 + (size_t)b * 3 * N_;
    float px = qp[n], py = qp[N_ + n], pz = qp[2 * N_ + n];
    float px2 = -2.f * px, py2 = -2.f * py, pz2 = -2.f * pz;
    const float* base = pts + c * 516;
    float b0 = 1e30f, b1v = 1e30f, b2v = 1e30f;
    int i0 = 0, i1 = 0, i2 = 0;
    int mb = c * 128;
#pragma unroll 4
    for (int i = 0; i < 128; ++i) {
        f32x4 pv = *(const f32x4*)(base + i * 4);
        float d = fmaf(pv[0], px2, fmaf(pv[1], py2, fmaf(pv[2], pz2, pv[3])));
        int m = mb + i;
        bool c0 = d < b0, c1 = d < b1v, c2 = d < b2v;
        float nb1 = __builtin_amdgcn_fmed3f(d, b0, b1v);
        float nb2 = __builtin_amdgcn_fmed3f(d, b1v, b2v);
        i2 = c1 ? i1 : (c2 ? m : i2);
        i1 = c0 ? i0 : (c1 ? m : i1);
        i0 = c0 ? m : i0;
        b0 = fminf(b0, d);
        b1v = nb1; b2v = nb2;
    }
#pragma unroll
    for (int st = 1; st <= 4; st <<= 1) {
        float d0 = __shfl_xor(b0, st, 64);  int j0 = __shfl_xor(i0, st, 64);
        float d1 = __shfl_xor(b1v, st, 64); int j1 = __shfl_xor(i1, st, 64);
        float d2 = __shfl_xor(b2v, st, 64); int j2 = __shfl_xor(i2, st, 64);
#pragma unroll
        for (int e = 0; e < 3; ++e) {
            float d = (e == 0) ? d0 : (e == 1) ? d1 : d2;
            int   m = (e == 0) ? j0 : (e == 1) ? j1 : j2;
            bool c0 = d < b0, c1 = d < b1v, c2 = d < b2v;
            float nb1 = __builtin_amdgcn_fmed3f(d, b0, b1v);
            float nb2 = __builtin_amdgcn_fmed3f(d, b1v, b2v);
            i2 = c1 ? i1 : (c2 ? m : i2);
            i1 = c0 ? i0 : (c1 ? m : i1);
            i0 = c0 ? m : i0;
            b0 = fminf(b0, d);
            b1v = nb1; b2v = nb2;
        }
    }
    if ((lane & 7) == 0) {
        float sq1 = fmaf(px, px, fmaf(py, py, pz * pz));
        float e0 = fmaxf(sqrtf(fmaxf(b0 + sq1, 1e-20f)), 1e-10f);
        float e1 = fmaxf(sqrtf(fmaxf(b1v + sq1, 1e-20f)), 1e-10f);
        float e2 = fmaxf(sqrtf(fmaxf(b2v + sq1, 1e-20f)), 1e-10f);
        float r0 = 1.f / e0, r1 = 1.f / e1, r2 = 1.f / e2;
        float s = r0 + r1 + r2;
        size_t j = ((size_t)b * N_ + n) * 3;
        idxb[j] = i0; idxb[j + 1] = i1; idxb[j + 2] = i2;
        wb[j] = r0 / s; wb[j + 1] = r1 / s; wb[j + 2] = r2 / s;
    }
}

// ---------------------------------------------------------------------------
// W1/W2 fp32 -> fp16 (row-major (O,K) kept: that IS the A-fragment layout).
// ---------------------------------------------------------------------------
__global__ __launch_bounds__(256)
void convert_w_kernel(const float* __restrict__ W1, const float* __restrict__ W2,
                      _Float16* __restrict__ W1h, _Float16* __restrict__ W2h) {
    int t = blockIdx.x * 256 + threadIdx.x;
    if (t < O1_ * K0_) W1h[t] = (_Float16)W1[t];
    if (t < O2_ * O1_) W2h[t] = (_Float16)W2[t];
}

// ---------------------------------------------------------------------------
// Generic (C,NP) fp32 -> (NP,C) fp16 transpose via 64x64 LDS tile.
// Used for points2 -> p2T and points1 -> p1T.
// ---------------------------------------------------------------------------
__global__ __launch_bounds__(256)
void transpose_f16_kernel(const float* __restrict__ in, _Float16* __restrict__ out,
                          int NP, size_t in_bstride, size_t out_bstride,
                          int out_rstride) {
    __shared__ float tile[64][65];
    int t = threadIdx.x;
    int nb = blockIdx.x * 64, cb = blockIdx.y * 64;
    const float* ib = in + blockIdx.z * in_bstride;
#pragma unroll
    for (int r = 0; r < 16; ++r) {
        int cc = r * 4 + (t >> 6);
        tile[cc][t & 63] = ib[(size_t)(cb + cc) * NP + nb + (t & 63)];
    }
    __syncthreads();
    _Float16* ob = out + blockIdx.z * out_bstride;
#pragma unroll
    for (int pass = 0; pass < 2; ++pass) {
        int id = pass * 256 + t;
        int nl = id >> 3;
        int c8 = (id & 7) * 8;
        half8 v;
#pragma unroll
        for (int jj = 0; jj < 8; ++jj) v[jj] = (_Float16)tile[c8 + jj][nl];
        *(half8*)(ob + (size_t)(nb + nl) * out_rstride + cb + c8) = v;
    }
}

// ---------------------------------------------------------------------------
// Fused v3: cooperative staged X-tile (interp once per block, fp32 accum) in
// swizzled LDS -> GEMM1(relu) -> swizzled LDS Y1 -> GEMM2(relu) -> out.
// Block: 64 n-rows, 512 threads (8 waves = 4 o-groups x 2 n-groups).
// LDS: X 64x768B (48KB) + Y1 64x512B (32KB) = 80KB -> 2 blocks/CU.
// ---------------------------------------------------------------------------
__global__ __launch_bounds__(512, 4)
void fused_mlp_kernel(const _Float16* __restrict__ p2T, const int* __restrict__ idxb,
                      const float* __restrict__ wb, const float* __restrict__ points1,
                      const _Float16* __restrict__ p1T,
                      const _Float16* __restrict__ W1h, const float* __restrict__ b1,
                      const _Float16* __restrict__ W2h, const float* __restrict__ b2,
                      float* __restrict__ out) {
    extern __shared__ char smem[];
    char* Xs = smem;                  // row n: 768B (384 fp16), XOR-swizzled
    char* Ys = smem + 64 * 768;       // row n: 512B (256 fp16), XOR-swizzled
    int b = blockIdx.y;
    int n0b = blockIdx.x * 64;
    int t = threadIdx.x, lane = t & 63, wv = t >> 6;
    int lr = lane & 15, lh = lane >> 4;

    // ---- stage X: interp (fp32 accumulate) + points1, swizzled writes ----
    {
        int row = t >> 3, seg = t & 7;        // 64 rows x 8 col-segments
        size_t j = ((size_t)b * N_ + n0b + row) * 3;
        int i0 = idxb[j], i1 = idxb[j + 1], i2 = idxb[j + 2];
        float w0 = wb[j], w1 = wb[j + 1], w2 = wb[j + 2];
        const _Float16* pb = p2T + (size_t)b * M_ * C2_;
        const half8* q0 = (const half8*)(pb + (size_t)i0 * C2_ + seg * 32);
        const half8* q1 = (const half8*)(pb + (size_t)i1 * C2_ + seg * 32);
        const half8* q2 = (const half8*)(pb + (size_t)i2 * C2_ + seg * 32);
        half8 a0[4] = {q0[0], q0[1], q0[2], q0[3]};
        half8 a1[4] = {q1[0], q1[1], q1[2], q1[3]};
        half8 a2[4] = {q2[0], q2[1], q2[2], q2[3]};
        int rswz = (row & 7) << 4;
        char* xrow = Xs + row * 768;
#pragma unroll
        for (int x = 0; x < 4; ++x) {
            half8 v;
#pragma unroll
            for (int jj = 0; jj < 8; ++jj)
                v[jj] = (_Float16)(w0 * (float)a0[x][jj] + w1 * (float)a1[x][jj]
                                 + w2 * (float)a2[x][jj]);
            *(half8*)(xrow + ((seg * 64 + x * 16) ^ rswz)) = v;
        }
        if (p1T) {
            const half8* q3 = (const half8*)(p1T + ((size_t)b * N_ + n0b + row) * C1_ + seg * 16);
            half8 c0v = q3[0], c1v = q3[1];
            *(half8*)(xrow + ((512 + seg * 32) ^ rswz)) = c0v;
            *(half8*)(xrow + ((512 + seg * 32 + 16) ^ rswz)) = c1v;
        } else {
            const float* pp = points1 + ((size_t)b * C1_ + seg * 16) * N_ + n0b + row;
            half8 c0v, c1v;
#pragma unroll
            for (int jj = 0; jj < 8; ++jj) c0v[jj] = (_Float16)pp[(size_t)jj * N_];
#pragma unroll
            for (int jj = 0; jj < 8; ++jj) c1v[jj] = (_Float16)pp[(size_t)(8 + jj) * N_];
            *(half8*)(xrow + ((512 + seg * 32) ^ rswz)) = c0v;
            *(half8*)(xrow + ((512 + seg * 32 + 16) ^ rswz)) = c1v;
        }
    }
    __syncthreads();

    int wvo = wv & 3, wvn = wv >> 2;
    int r0 = wvn * 32 + lr;           // nf=0 row; nf=1 row = r0+16 (same swizzle)
    int swz = (r0 & 7) << 4;
    char* x0 = Xs + r0 * 768;
    char* x1 = x0 + 16 * 768;

    // ---- phase 1: Y1 = relu(W1 * X^T + b1); wave tile 64o x 32n ----
    f32x4 acc[4][2];
#pragma unroll
    for (int of = 0; of < 4; ++of) {
        int o = wvo * 64 + of * 16 + lh * 4;
        f32x4 bv = {b1[o], b1[o + 1], b1[o + 2], b1[o + 3]};
        acc[of][0] = bv; acc[of][1] = bv;
    }
    const _Float16* w1p = W1h + (size_t)(wvo * 64 + lr) * K0_ + lh * 8;
#pragma unroll
    for (int k0 = 0; k0 < K0_; k0 += 32) {
        half8 bf0 = *(const half8*)(x0 + ((k0 * 2 + lh * 16) ^ swz));
        half8 bf1 = *(const half8*)(x1 + ((k0 * 2 + lh * 16) ^ swz));
#pragma unroll
        for (int of = 0; of < 4; ++of) {
            half8 af = *(const half8*)(w1p + (size_t)of * 16 * K0_ + k0);
            acc[of][0] = __builtin_amdgcn_mfma_f32_16x16x32_f16(af, bf0, acc[of][0], 0, 0, 0);
            acc[of][1] = __builtin_amdgcn_mfma_f32_16x16x32_f16(af, bf1, acc[of][1], 0, 0, 0);
        }
    }
    // epilogue 1: relu -> fp16 -> swizzled Ys
#pragma unroll
    for (int of = 0; of < 4; ++of) {
#pragma unroll
        for (int nf = 0; nf < 2; ++nf) {
            int nrow = wvn * 32 + nf * 16 + lr;
            int obyte = (wvo * 64 + of * 16 + lh * 4) * 2;
            half4 h;
#pragma unroll
            for (int r = 0; r < 4; ++r) h[r] = (_Float16)fmaxf(acc[of][nf][r], 0.f);
            *(half4*)(Ys + ((nrow * 512 + obyte) ^ ((nrow & 7) << 4))) = h;
        }
    }
    __syncthreads();

    // ---- phase 2: out = relu(W2 * Y1^T + b2); wave tile 64o2 x 32n ----
    f32x4 acc2[4][2];
#pragma unroll
    for (int of = 0; of < 4; ++of) {
        int o = wvo * 64 + of * 16 + lh * 4;
        f32x4 bv = {b2[o], b2[o + 1], b2[o + 2], b2[o + 3]};
        acc2[of][0] = bv; acc2[of][1] = bv;
    }
    const _Float16* w2p = W2h + (size_t)(wvo * 64 + lr) * O1_ + lh * 8;
    char* y0 = Ys + r0 * 512;
    char* y1 = y0 + 16 * 512;
#pragma unroll
    for (int k0 = 0; k0 < O1_; k0 += 32) {
        half8 bb0 = *(const half8*)(y0 + ((k0 * 2 + lh * 16) ^ swz));
        half8 bb1 = *(const half8*)(y1 + ((k0 * 2 + lh * 16) ^ swz));
#pragma unroll
        for (int of = 0; of < 4; ++of) {
            half8 af = *(const half8*)(w2p + (size_t)of * 16 * O1_ + k0);
            acc2[of][0] = __builtin_amdgcn_mfma_f32_16x16x32_f16(af, bb0, acc2[of][0], 0, 0, 0);
            acc2[of][1] = __builtin_amdgcn_mfma_f32_16x16x32_f16(af, bb1, acc2[of][1], 0, 0, 0);
        }
    }
    float* ob = out + (size_t)b * O2_ * N_;
#pragma unroll
    for (int of = 0; of < 4; ++of) {
#pragma unroll
        for (int r = 0; r < 4; ++r) {
            int o2 = wvo * 64 + of * 16 + lh * 4 + r;
#pragma unroll
            for (int nf = 0; nf < 2; ++nf) {
                int n = n0b + wvn * 32 + nf * 16 + lr;
                ob[(size_t)o2 * N_ + n] = fmaxf(acc2[of][nf][r], 0.f);
            }
        }
    }
}

// ---------------------------------------------------------------------------
extern "C" void kernel_launch(void* const* d_in, const int* in_sizes, int n_in,
                              void* d_out, int out_size, void* d_ws, size_t ws_size,
                              hipStream_t stream) {
    const float* xyz1    = (const float*)d_in[0];
    const float* xyz2    = (const float*)d_in[1];
    const float* points1 = (const float*)d_in[2];
    const float* points2 = (const float*)d_in[3];
    const float* W1      = (const float*)d_in[4];
    const float* b1      = (const float*)d_in[5];
    const float* W2      = (const float*)d_in[6];
    const float* b2      = (const float*)d_in[7];
    float* out = (float*)d_out;
    (void)in_sizes; (void)n_in; (void)out_size;

    char* p = (char*)d_ws;
    auto alloc = [&](size_t bytes) -> char* {
        char* r = p;
        p += (bytes + 255) & ~(size_t)255;
        return r;
    };
    _Float16* W1h  = (_Float16*)alloc((size_t)O1_ * K0_ * 2);
    _Float16* W2h  = (_Float16*)alloc((size_t)O2_ * O1_ * 2);
    int*      idxb = (int*)alloc((size_t)B_ * N_ * 3 * 4);
    float*    wbuf = (float*)alloc((size_t)B_ * N_ * 3 * 4);
    _Float16* p2T  = (_Float16*)alloc((size_t)B_ * M_ * C2_ * 2);
    size_t used = (size_t)(p - (char*)d_ws);
    size_t p1T_bytes = (size_t)B_ * N_ * C1_ * 2;
    _Float16* p1T = nullptr;
    if (ws_size >= used + p1T_bytes)
        p1T = (_Float16*)alloc(p1T_bytes);

    convert_w_kernel<<<dim3((O1_ * K0_ + 255) / 256), 256, 0, stream>>>(W1, W2, W1h, W2h);
    three_nn_kernel<<<dim3(N_ / 32, B_), 256, 0, stream>>>(xyz1, xyz2, idxb, wbuf);
    transpose_f16_kernel<<<dim3(M_ / 64, C2_ / 64, B_), 256, 0, stream>>>(
        points2, p2T, M_, (size_t)C2_ * M_, (size_t)M_ * C2_, C2_);
    if (p1T)
        transpose_f16_kernel<<<dim3(N_ / 64, C1_ / 64, B_), 256, 0, stream>>>(
            points1, p1T, N_, (size_t)C1_ * N_, (size_t)N_ * C1_, C1_);
    fused_mlp_kernel<<<dim3(N_ / 64, B_), 512, 64 * 768 + 64 * 512, stream>>>(
        p2T, idxb, wbuf, points1, p1T, W1h, b1, W2h, b2, out);
}